// Round 8
// baseline (211.985 us; speedup 1.0000x reference)
//
#include <hip/hip_runtime.h>
#include <math.h>

#define PI_F 3.14159265358979323846f
#define TWO_PI_F 6.28318530717958647692f
#define RSQ2 0.70710678118654752440f

// counted DS waits: DS ops retire in issue order within a wave, so
// lgkmcnt(8) after issuing 8 younger ops proves all older DS ops are done.
#define LGKM(n) __asm__ volatile("s_waitcnt lgkmcnt(" #n ")" ::: "memory")
// additive swizzle: injective on [0,512), max 574; breaks the 2-bank
// degeneracy of the stage-0 write pattern (8j+i).
#define LADDR(a) ((a) + ((a) >> 3))

__device__ __forceinline__ float2 cadd(float2 a, float2 b){ return make_float2(a.x+b.x, a.y+b.y); }
__device__ __forceinline__ float2 csub(float2 a, float2 b){ return make_float2(a.x-b.x, a.y-b.y); }
__device__ __forceinline__ float2 cmul(float2 a, float2 b){ return make_float2(a.x*b.x - a.y*b.y, a.x*b.y + a.y*b.x); }
__device__ __forceinline__ float2 cw1(float2 a){ return make_float2(RSQ2*(a.x+a.y), RSQ2*(a.y-a.x)); }  // *W8^1
__device__ __forceinline__ float2 cw2(float2 a){ return make_float2(a.y, -a.x); }                        // *(-i)
__device__ __forceinline__ float2 cw3(float2 a){ return make_float2(RSQ2*(a.y-a.x), -RSQ2*(a.x+a.y)); }  // *W8^3

// in-place DIF-8. On return, slot m holds U_{br[m]}, br = {0,4,2,6,1,5,3,7}.
__device__ __forceinline__ void dft8(float2* v){
    float2 a0=cadd(v[0],v[4]), a1=cadd(v[1],v[5]), a2=cadd(v[2],v[6]), a3=cadd(v[3],v[7]);
    float2 b0=csub(v[0],v[4]);
    float2 b1=cw1(csub(v[1],v[5]));
    float2 b2=cw2(csub(v[2],v[6]));
    float2 b3=cw3(csub(v[3],v[7]));
    float2 c0=cadd(a0,a2), c2=csub(a0,a2), c1=cadd(a1,a3), c3=cw2(csub(a1,a3));
    float2 d0=cadd(b0,b2), d2=csub(b0,b2), d1=cadd(b1,b3), d3=cw2(csub(b1,b3));
    v[0]=cadd(c0,c1); v[1]=csub(c0,c1);   // U0, U4
    v[2]=cadd(c2,c3); v[3]=csub(c2,c3);   // U2, U6
    v[4]=cadd(d0,d1); v[5]=csub(d0,d1);   // U1, U5
    v[6]=cadd(d2,d3); v[7]=csub(d2,d3);   // U3, U7
}

// twiddle powers w^1..w^7 via log-depth tree
__device__ __forceinline__ void calc_pows(float2 w, float2* p){
    p[0] = w;
    p[1] = cmul(w, w);          // w^2
    p[2] = cmul(p[1], w);       // w^3
    p[3] = cmul(p[1], p[1]);    // w^4
    p[4] = cmul(p[2], p[1]);    // w^5
    p[5] = cmul(p[2], p[2]);    // w^6
    p[6] = cmul(p[3], p[2]);    // w^7
}

// Stockham radix-8 stage store: address-slot c gets U_c * w^c at base+step*c.
__device__ __forceinline__ void stage_store(float2* wl, const float2* v, const float2* p,
                                            int base, int step){
    constexpr int br[8] = {0,4,2,6,1,5,3,7};
    wl[LADDR(base)] = v[0];
    #pragma unroll
    for (int c = 1; c < 8; ++c) wl[LADDR(base + step*c)] = cmul(v[br[c]], p[c-1]);
}

__device__ __forceinline__ void stage_load(const float2* wl, float2* v, int j){
    #pragma unroll
    for (int i = 0; i < 8; ++i) v[i] = wl[LADDR(j + 64*i)];
}

// ---- the R2-proven dual-buffer counted-lgkm 512-pt FFT on two streams ----
__device__ __forceinline__ void fft512_pair(float2* va, float2* vb,
                                            float2* wlA, float2* wlB,
                                            float2 tw0, float2 tw1, int j){
    float2 pw[7];
    calc_pows(tw0, pw);
    dft8(va);
    dft8(vb);
    stage_store(wlA, va, pw, 8 * j, 1);
    stage_store(wlB, vb, pw, 8 * j, 1);
    LGKM(8);                              // A writes done
    stage_load(wlA, va, j);
    LGKM(8);                              // B writes done
    stage_load(wlB, vb, j);
    LGKM(8);                              // A reads done (B reads in flight)
    calc_pows(tw1, pw);
    dft8(va);
    stage_store(wlA, va, pw, (j & 7) + 64 * (j >> 3), 8);
    LGKM(8);                              // B reads done (A writes in flight)
    dft8(vb);
    stage_store(wlB, vb, pw, (j & 7) + 64 * (j >> 3), 8);
    LGKM(8);                              // A writes done
    stage_load(wlA, va, j);
    LGKM(8);                              // B writes done
    stage_load(wlB, vb, j);
    LGKM(8);                              // A reads done (B reads in flight)
    dft8(va);
    LGKM(0);                              // B reads done
    dft8(vb);
}

// ---------------- sector map (matches reference _polar_masks) ----------------
__device__ __forceinline__ int sector_id(int hm, int wm) {
    const float step = 2.0f / 511.0f;
    float y = -1.0f + step * (float)hm;
    float x = -1.0f + step * (float)wm;
    float radius = sqrtf(x * x + y * y);
    float r = radius / sqrtf(2.0f);
    float a = atan2f(y, x);
    a = fmodf(a, PI_F);
    if (a < 0.0f) a += PI_F;

    const float rstep = (0.9f - 0.08f) / 3.0f;
    const float re0 = 0.08f;
    const float re1 = 0.08f + rstep;
    const float re2 = 0.08f + 2.0f * rstep;
    const float re3 = 0.9f;
    int rb;
    if      (r >= re0 && r < re1)  rb = 0;
    else if (r >= re1 && r < re2)  rb = 1;
    else if (r >= re2 && r <= re3) rb = 2;
    else return -1;

    const float astep = PI_F / 8.0f;
    int ab = 7;
    #pragma unroll
    for (int i = 0; i < 7; ++i) {
        float t0 = astep * (float)i;
        float t1 = astep * (float)(i + 1);
        if (a >= t0 && a < t1) { ab = i; break; }
    }
    return rb * 8 + ab;
}

__device__ __forceinline__ float hannf(int i) {
    return 0.5f * (1.0f - __cosf(TWO_PI_F * (float)i / 511.0f));
}

__device__ __forceinline__ float lumaf(const float* b, size_t off){
    return 0.2989f*b[off] + 0.587f*b[off+262144] + 0.114f*b[off+524288];
}

// Hermitian unpack + TRANSPOSED store: buf4[img][hp][k] (k fast). Lane j
// writes k=j+64c at fixed hp -> each store = 64 lanes x 16B contiguous = 1KB
// full-line coalesced.
__device__ __forceinline__ void write_row_T(float4* __restrict__ out4, size_t ibase, int hp,
                                            const float2* v, int partner, int j){
    constexpr int br[8] = {0,4,2,6,1,5,3,7};
    float4* row = out4 + (ibase + (size_t)hp) * 256;
    #pragma unroll
    for (int c = 0; c < 4; ++c) {
        int k = j + 64 * c;
        float2 zk = v[br[c]];
        float mx = __shfl(v[br[7 - c]].x, partner, 64);
        float my = __shfl(v[br[7 - c]].y, partner, 64);
        float2 zs = v[br[(8 - c) & 7]];
        float2 zm = make_float2(j == 0 ? zs.x : mx, j == 0 ? zs.y : my);
        float4 o = make_float4(0.5f*(zk.x+zm.x), 0.5f*(zk.y-zm.y),
                               0.5f*(zk.y+zm.y), 0.5f*(zm.x-zk.x));
        if (k != 0) row[k] = o;
    }
    if (j == 0) {                         // packed real pair: (F_h[0], F_h[256])
        float2 z0 = v[br[0]], z4 = v[br[4]];
        row[0] = make_float4(z0.x, z4.x, z0.y, z4.y);
    }
}

// log-magnitude binning for one normal column (mirrored partner included).
__device__ __forceinline__ void bin_col(const float2* v,
                                        const unsigned char* __restrict__ mw1,
                                        const unsigned char* __restrict__ mw2,
                                        float* wb, int rep, int j){
    constexpr int br[8] = {0,4,2,6,1,5,3,7};
    #pragma unroll
    for (int c = 0; c < 8; ++c) {
        float2 z = v[br[c]];              // Z[h = j + 64c]
        float mag = __logf(1.0f + sqrtf(z.x * z.x + z.y * z.y));
        int hm = j + 64 * ((c + 4) & 7);  // (h+256)&511
        int s1 = mw1[hm]; if (s1 < 24) atomicAdd(&wb[rep + s1], mag);
        int hm2 = (256 - (j + 64 * c)) & 511;
        int s2 = mw2[hm2]; if (s2 < 24) atomicAdd(&wb[rep + s2], mag);
    }
}

// ---------------- kernel 1: luma + window + row FFT (R7-frozen) -------------
__global__ __launch_bounds__(256, 4) void rowfft_kernel(const float* __restrict__ pred,
                                                        const float* __restrict__ tgt,
                                                        float4* __restrict__ out4,
                                                        unsigned char* __restrict__ mapT,
                                                        unsigned short* __restrict__ cnt_u16,
                                                        float* __restrict__ acc_rep) {
    __shared__ float2 lds[4 * 1152];
    __shared__ float cbins[24];
    int blk = blockIdx.x;                 // 32 img * 32
    int img = blk >> 5;
    int pb  = blk & 31;
    int t = threadIdx.x;
    int wv = t >> 6, j = t & 63;
    int hpA = pb * 8 + wv * 2;            // row-pair indices [0,256)
    int hpB = hpA + 1;
    int h0 = 2 * hpA;                     // rows h0..h0+3
    float2* wlA = lds + wv * 1152;
    float2* wlB = wlA + 576;

    if (blk < 48) acc_rep[blk * 256 + t] = 0.0f;   // zero 16*768 replica floats
    if (t < 24) cbins[t] = 0.0f;
    __syncthreads();
    {                                     // folded sector map + per-block counts
        int idx = blk * 256 + t;          // idx = wm*512 + hm ; 1024*256 = full map
        int wm = idx >> 9, hm = idx & 511;
        int s = sector_id(hm, wm);
        mapT[idx] = (unsigned char)(s < 0 ? 255 : s);
        if (s >= 0) atomicAdd(&cbins[s], 1.0f);
    }

    const float* base = (img < 16) ? (pred + (size_t)img * 786432)
                                   : (tgt  + (size_t)(img - 16) * 786432);
    float whA0 = hannf(h0), whA1 = hannf(h0 + 1);
    float whB0 = hannf(h0 + 2), whB1 = hannf(h0 + 3);
    float2 va[8], vb[8];
    #pragma unroll
    for (int i = 0; i < 8; ++i) {
        int w = j + 64 * i;
        float ww = hannf(w);
        size_t off0 = (size_t)h0 * 512 + w;
        float l0 = lumaf(base, off0);
        float l1 = lumaf(base, off0 + 512);
        float l2 = lumaf(base, off0 + 1024);
        float l3 = lumaf(base, off0 + 1536);
        va[i] = make_float2(l0 * (whA0 * ww), l1 * (whA1 * ww));
        vb[i] = make_float2(l2 * (whB0 * ww), l3 * (whB1 * ww));
    }

    float sn, cs;
    __sincosf(-TWO_PI_F * (float)j / 512.0f, &sn, &cs);
    float2 tw0 = make_float2(cs, sn);
    __sincosf(-TWO_PI_F * (float)((j >> 3) << 3) / 512.0f, &sn, &cs);
    float2 tw1 = make_float2(cs, sn);

    fft512_pair(va, vb, wlA, wlB, tw0, tw1, j);   // R2-proven schedule

    size_t ibase = (size_t)img * 256;
    int partner = (64 - j) & 63;
    write_row_T(out4, ibase, hpA, va, partner, j);
    write_row_T(out4, ibase, hpB, vb, partner, j);

    __syncthreads();
    if (t < 24) cnt_u16[t * 1024 + blk] = (unsigned short)(int)cbins[t];
}

// ---------------- kernel 2: column FFT + log-mag + sector bins ----------------
// ONE WAVE PER BLOCK: 4096 blocks x 64 threads, 2 adjacent columns per wave
// (R2-proven body, transposed-buf reads). LDS 9216B/block -> ~17 blocks/CU by
// LDS, grid needs exactly 16/CU = one generation at a 16-wave/CU ceiling (2x
// R7's 8): more independent latency chains per SIMD, no block co-scheduling.
__global__ __launch_bounds__(64, 6) void colfft_kernel(const float4* __restrict__ buf4,
                                                       const unsigned char* __restrict__ mapT,
                                                       float* __restrict__ acc_rep) {
    __shared__ float2 lds[2 * 576];
    int j = threadIdx.x;                  // 0..63 (single wave)
    int pg = blockIdx.x;                  // pair id 0..4095
    int img = pg >> 7;                    // 128 pairs per img
    int pl = pg & 127;
    int wA = 2 * pl, wB = wA + 1;         // wA even, wB odd in [1,255]
    float2* wlA = lds;
    float2* wlB = lds + 576;

    const float4* b4 = buf4 + ((size_t)img * 256) * 256 + wA;
    float2 va[8], vb[8];
    #pragma unroll
    for (int i = 0; i < 8; ++i) {
        int h = j + 64 * i;
        const float4* row = b4 + (size_t)(h >> 1) * 256;
        float4 q0 = row[0], q1 = row[1];
        bool odd = (h & 1) != 0;
        va[i] = odd ? make_float2(q0.z, q0.w) : make_float2(q0.x, q0.y);
        vb[i] = odd ? make_float2(q1.z, q1.w) : make_float2(q1.x, q1.y);
    }

    float sn, cs;
    __sincosf(-TWO_PI_F * (float)j / 512.0f, &sn, &cs);
    float2 tw0 = make_float2(cs, sn);
    __sincosf(-TWO_PI_F * (float)((j >> 3) << 3) / 512.0f, &sn, &cs);
    float2 tw1 = make_float2(cs, sn);

    fft512_pair(va, vb, wlA, wlB, tw0, tw1, j);   // R2-proven schedule

    float* wb = (float*)wlA;              // FFT scratch dead -> 8 replicas x 25 bins
    #pragma unroll
    for (int i = 0; i < 4; ++i) { int ii = j + 64 * i; if (ii < 200) wb[ii] = 0.0f; }
    LGKM(0);

    constexpr int br[8] = {0,4,2,6,1,5,3,7};
    int rep = (j & 7) * 25;               // 25*r mod 32 distinct for r in [0,8)
    bool pairw = (wA == 0);               // stream A = packed real columns 0 & 256
    if (pairw) {
        // unpack two real-column FFTs: F0[k]=(Z[k]+conj(Z[-k]))/2,
        // F256[k]=(Z[k]-conj(Z[-k]))/(2i)
        int partner = (64 - j) & 63;
        const unsigned char* mwA1 = mapT + (size_t)256 * 512;   // col w=0   -> wm=256
        const unsigned char* mwA2 = mapT;                       // col w=256 -> wm=0
        #pragma unroll
        for (int c = 0; c < 8; ++c) {
            float2 zk = va[br[c]];
            float mx = __shfl(va[br[7 - c]].x, partner, 64);
            float my = __shfl(va[br[7 - c]].y, partner, 64);
            float2 zs = va[br[(8 - c) & 7]];
            float2 zm = make_float2(j == 0 ? zs.x : mx, j == 0 ? zs.y : my);
            float f0x = 0.5f*(zk.x+zm.x), f0y = 0.5f*(zk.y-zm.y);
            float f1x = 0.5f*(zk.y+zm.y), f1y = 0.5f*(zm.x-zk.x);
            float mag0 = __logf(1.0f + sqrtf(f0x*f0x + f0y*f0y));
            float mag1 = __logf(1.0f + sqrtf(f1x*f1x + f1y*f1y));
            int hm = j + 64 * ((c + 4) & 7);
            int s1 = mwA1[hm]; if (s1 < 24) atomicAdd(&wb[rep + s1], mag0);
            int s2 = mwA2[hm]; if (s2 < 24) atomicAdd(&wb[rep + s2], mag1);
        }
    } else {
        bin_col(va, mapT + (size_t)((wA + 256) & 511) * 512,
                    mapT + (size_t)((256 - wA) & 511) * 512, wb, rep, j);
    }
    bin_col(vb, mapT + (size_t)((wB + 256) & 511) * 512,
                mapT + (size_t)((256 - wB) & 511) * 512, wb, rep, j);
    LGKM(0);
    if (j < 24) {
        float sum = 0.0f;
        #pragma unroll
        for (int r = 0; r < 8; ++r) sum += wb[r * 25 + j];
        atomicAdd(&acc_rep[(pg & 15) * 768 + img * 24 + j], sum);
    }
}

// ---------------- kernel 3: reduce replicas/partials -> loss ----------------
__global__ __launch_bounds__(256) void final_kernel(const float* __restrict__ acc_rep,
                                                    const unsigned short* __restrict__ cnt_u16,
                                                    const float* __restrict__ rw,
                                                    float* __restrict__ out) {
    __shared__ float accs[768];
    __shared__ float cnts[24];
    __shared__ float ep[384], et[384], red[384];
    int t = threadIdx.x;
    for (int o = t; o < 768; o += 256) {           // sum 16 replicas (coalesced)
        float s = 0.0f;
        #pragma unroll
        for (int r = 0; r < 16; ++r) s += acc_rep[r * 768 + o];
        accs[o] = s;
    }
    if (t < 192) {                                 // counts: 24 sectors x 8 lanes
        int s = t >> 3, g = t & 7;
        const ushort4* p = (const ushort4*)(cnt_u16 + s * 1024 + g * 128);
        float sum = 0.0f;
        #pragma unroll
        for (int i = 0; i < 32; ++i) { ushort4 u = p[i]; sum += (float)(u.x + u.y + u.z + u.w); }
        sum += __shfl_down(sum, 4, 8);
        sum += __shfl_down(sum, 2, 8);
        sum += __shfl_down(sum, 1, 8);
        if (g == 0) cnts[s] = sum;
    }
    __syncthreads();
    for (int idx = t; idx < 384; idx += 256) {     // idx = b*24 + s, b in [0,16)
        int b = idx / 24, s = idx - b * 24;
        float cnt = fmaxf(cnts[s], 1e-6f);
        ep[idx] = accs[b * 24 + s] / cnt;
        et[idx] = accs[(16 + b) * 24 + s] / cnt;
    }
    __syncthreads();
    for (int idx = t; idx < 384; idx += 256) {
        int b = idx / 24, s = idx - b * 24, r = s >> 3;
        int gbase = b * 24 + r * 8;
        float sp = 0.0f, st = 0.0f;
        #pragma unroll
        for (int a = 0; a < 8; ++a) { sp += ep[gbase + a]; st += et[gbase + a]; }
        float pe = ep[idx] / fmaxf(sp, 1e-6f);
        float te = et[idx] / fmaxf(st, 1e-6f);
        float d = pe - te;
        red[idx] = sqrtf(d * d + 1e-6f) * rw[r];
    }
    __syncthreads();
    if (t < 128) red[t] += red[t + 128] + red[t + 256];
    __syncthreads();
    if (t < 64) {
        float vv = red[t] + red[t + 64];
        #pragma unroll
        for (int o = 32; o > 0; o >>= 1) vv += __shfl_down(vv, o, 64);
        if (t == 0) out[0] = vv / 384.0f;
    }
}

extern "C" void kernel_launch(void* const* d_in, const int* in_sizes, int n_in,
                              void* d_out, int out_size, void* d_ws, size_t ws_size,
                              hipStream_t stream) {
    const float* pred = (const float*)d_in[0];
    const float* tgt  = (const float*)d_in[1];
    const float* rw   = (const float*)d_in[2];

    char* ws = (char*)d_ws;
    float* acc_rep       = (float*)ws;                     // 16*768 floats = 49152 B
    unsigned short* cnt  = (unsigned short*)(ws + 49152);  // 24*1024*2     = 49152 B
    unsigned char* mapT  = (unsigned char*)(ws + 98304);   // 512*512       = 262144 B
    float4* buf4         = (float4*)(ws + 360448);         // 32*256*256*16 = 33.55 MB

    rowfft_kernel<<<1024, 256, 0, stream>>>(pred, tgt, buf4, mapT, cnt, acc_rep);
    colfft_kernel<<<4096, 64, 0, stream>>>(buf4, mapT, acc_rep);
    final_kernel<<<1, 256, 0, stream>>>(acc_rep, cnt, rw, (float*)d_out);
}

// Round 9
// 186.962 us; speedup vs baseline: 1.1338x; 1.1338x over previous
//
#include <hip/hip_runtime.h>
#include <math.h>

#define PI_F 3.14159265358979323846f
#define TWO_PI_F 6.28318530717958647692f
#define RSQ2 0.70710678118654752440f

// counted DS waits: DS ops retire in issue order within a wave, so
// lgkmcnt(8) after issuing 8 younger ops proves all older DS ops are done.
#define LGKM(n) __asm__ volatile("s_waitcnt lgkmcnt(" #n ")" ::: "memory")
// additive swizzle: injective on [0,512), max 574; breaks the 2-bank
// degeneracy of the stage-0 write pattern (8j+i).
#define LADDR(a) ((a) + ((a) >> 3))

__device__ __forceinline__ float2 cadd(float2 a, float2 b){ return make_float2(a.x+b.x, a.y+b.y); }
__device__ __forceinline__ float2 csub(float2 a, float2 b){ return make_float2(a.x-b.x, a.y-b.y); }
__device__ __forceinline__ float2 cmul(float2 a, float2 b){ return make_float2(a.x*b.x - a.y*b.y, a.x*b.y + a.y*b.x); }
__device__ __forceinline__ float2 cw1(float2 a){ return make_float2(RSQ2*(a.x+a.y), RSQ2*(a.y-a.x)); }  // *W8^1
__device__ __forceinline__ float2 cw2(float2 a){ return make_float2(a.y, -a.x); }                        // *(-i)
__device__ __forceinline__ float2 cw3(float2 a){ return make_float2(RSQ2*(a.y-a.x), -RSQ2*(a.x+a.y)); }  // *W8^3

// in-place DIF-8. On return, slot m holds U_{br[m]}, br = {0,4,2,6,1,5,3,7}.
__device__ __forceinline__ void dft8(float2* v){
    float2 a0=cadd(v[0],v[4]), a1=cadd(v[1],v[5]), a2=cadd(v[2],v[6]), a3=cadd(v[3],v[7]);
    float2 b0=csub(v[0],v[4]);
    float2 b1=cw1(csub(v[1],v[5]));
    float2 b2=cw2(csub(v[2],v[6]));
    float2 b3=cw3(csub(v[3],v[7]));
    float2 c0=cadd(a0,a2), c2=csub(a0,a2), c1=cadd(a1,a3), c3=cw2(csub(a1,a3));
    float2 d0=cadd(b0,b2), d2=csub(b0,b2), d1=cadd(b1,b3), d3=cw2(csub(b1,b3));
    v[0]=cadd(c0,c1); v[1]=csub(c0,c1);   // U0, U4
    v[2]=cadd(c2,c3); v[3]=csub(c2,c3);   // U2, U6
    v[4]=cadd(d0,d1); v[5]=csub(d0,d1);   // U1, U5
    v[6]=cadd(d2,d3); v[7]=csub(d2,d3);   // U3, U7
}

// twiddle powers w^1..w^7 via log-depth tree
__device__ __forceinline__ void calc_pows(float2 w, float2* p){
    p[0] = w;
    p[1] = cmul(w, w);          // w^2
    p[2] = cmul(p[1], w);       // w^3
    p[3] = cmul(p[1], p[1]);    // w^4
    p[4] = cmul(p[2], p[1]);    // w^5
    p[5] = cmul(p[2], p[2]);    // w^6
    p[6] = cmul(p[3], p[2]);    // w^7
}

// Stockham radix-8 stage store: address-slot c gets U_c * w^c at base+step*c.
__device__ __forceinline__ void stage_store(float2* wl, const float2* v, const float2* p,
                                            int base, int step){
    constexpr int br[8] = {0,4,2,6,1,5,3,7};
    wl[LADDR(base)] = v[0];
    #pragma unroll
    for (int c = 1; c < 8; ++c) wl[LADDR(base + step*c)] = cmul(v[br[c]], p[c-1]);
}

__device__ __forceinline__ void stage_load(const float2* wl, float2* v, int j){
    #pragma unroll
    for (int i = 0; i < 8; ++i) v[i] = wl[LADDR(j + 64*i)];
}

// ---- the R2-proven dual-buffer counted-lgkm 512-pt FFT on two streams ----
__device__ __forceinline__ void fft512_pair(float2* va, float2* vb,
                                            float2* wlA, float2* wlB,
                                            float2 tw0, float2 tw1, int j){
    float2 pw[7];
    calc_pows(tw0, pw);
    dft8(va);
    dft8(vb);
    stage_store(wlA, va, pw, 8 * j, 1);
    stage_store(wlB, vb, pw, 8 * j, 1);
    LGKM(8);                              // A writes done
    stage_load(wlA, va, j);
    LGKM(8);                              // B writes done
    stage_load(wlB, vb, j);
    LGKM(8);                              // A reads done (B reads in flight)
    calc_pows(tw1, pw);
    dft8(va);
    stage_store(wlA, va, pw, (j & 7) + 64 * (j >> 3), 8);
    LGKM(8);                              // B reads done (A writes in flight)
    dft8(vb);
    stage_store(wlB, vb, pw, (j & 7) + 64 * (j >> 3), 8);
    LGKM(8);                              // A writes done
    stage_load(wlA, va, j);
    LGKM(8);                              // B writes done
    stage_load(wlB, vb, j);
    LGKM(8);                              // A reads done (B reads in flight)
    dft8(va);
    LGKM(0);                              // B reads done
    dft8(vb);
}

// ---------------- sector map (matches reference _polar_masks) ----------------
__device__ __forceinline__ int sector_id(int hm, int wm) {
    const float step = 2.0f / 511.0f;
    float y = -1.0f + step * (float)hm;
    float x = -1.0f + step * (float)wm;
    float radius = sqrtf(x * x + y * y);
    float r = radius / sqrtf(2.0f);
    float a = atan2f(y, x);
    a = fmodf(a, PI_F);
    if (a < 0.0f) a += PI_F;

    const float rstep = (0.9f - 0.08f) / 3.0f;
    const float re0 = 0.08f;
    const float re1 = 0.08f + rstep;
    const float re2 = 0.08f + 2.0f * rstep;
    const float re3 = 0.9f;
    int rb;
    if      (r >= re0 && r < re1)  rb = 0;
    else if (r >= re1 && r < re2)  rb = 1;
    else if (r >= re2 && r <= re3) rb = 2;
    else return -1;

    const float astep = PI_F / 8.0f;
    int ab = 7;
    #pragma unroll
    for (int i = 0; i < 7; ++i) {
        float t0 = astep * (float)i;
        float t1 = astep * (float)(i + 1);
        if (a >= t0 && a < t1) { ab = i; break; }
    }
    return rb * 8 + ab;
}

__device__ __forceinline__ float hannf(int i) {
    return 0.5f * (1.0f - __cosf(TWO_PI_F * (float)i / 511.0f));
}

__device__ __forceinline__ float lumaf(const float* b, size_t off){
    return 0.2989f*b[off] + 0.587f*b[off+262144] + 0.114f*b[off+524288];
}

// Hermitian unpack + TRANSPOSED store: buf4[img][hp][k] (k fast). Lane j
// writes k=j+64c at fixed hp -> each store = 64 lanes x 16B contiguous = 1KB
// full-line coalesced.
__device__ __forceinline__ void write_row_T(float4* __restrict__ out4, size_t ibase, int hp,
                                            const float2* v, int partner, int j){
    constexpr int br[8] = {0,4,2,6,1,5,3,7};
    float4* row = out4 + (ibase + (size_t)hp) * 256;
    #pragma unroll
    for (int c = 0; c < 4; ++c) {
        int k = j + 64 * c;
        float2 zk = v[br[c]];
        float mx = __shfl(v[br[7 - c]].x, partner, 64);
        float my = __shfl(v[br[7 - c]].y, partner, 64);
        float2 zs = v[br[(8 - c) & 7]];
        float2 zm = make_float2(j == 0 ? zs.x : mx, j == 0 ? zs.y : my);
        float4 o = make_float4(0.5f*(zk.x+zm.x), 0.5f*(zk.y-zm.y),
                               0.5f*(zk.y+zm.y), 0.5f*(zm.x-zk.x));
        if (k != 0) row[k] = o;
    }
    if (j == 0) {                         // packed real pair: (F_h[0], F_h[256])
        float2 z0 = v[br[0]], z4 = v[br[4]];
        row[0] = make_float4(z0.x, z4.x, z0.y, z4.y);
    }
}

// log-magnitude binning for one normal column (mirrored partner included).
__device__ __forceinline__ void bin_col(const float2* v,
                                        const unsigned char* __restrict__ mw1,
                                        const unsigned char* __restrict__ mw2,
                                        float* wb, int rep, int j){
    constexpr int br[8] = {0,4,2,6,1,5,3,7};
    #pragma unroll
    for (int c = 0; c < 8; ++c) {
        float2 z = v[br[c]];              // Z[h = j + 64c]
        float mag = __logf(1.0f + sqrtf(z.x * z.x + z.y * z.y));
        int hm = j + 64 * ((c + 4) & 7);  // (h+256)&511
        int s1 = mw1[hm]; if (s1 < 24) atomicAdd(&wb[rep + s1], mag);
        int hm2 = (256 - (j + 64 * c)) & 511;
        int s2 = mw2[hm2]; if (s2 < 24) atomicAdd(&wb[rep + s2], mag);
    }
}

// ---------------- kernel 1: luma + window + row FFT (R7-frozen) -------------
__global__ __launch_bounds__(256, 4) void rowfft_kernel(const float* __restrict__ pred,
                                                        const float* __restrict__ tgt,
                                                        float4* __restrict__ out4,
                                                        unsigned char* __restrict__ mapT,
                                                        unsigned short* __restrict__ cnt_u16,
                                                        float* __restrict__ acc_rep) {
    __shared__ float2 lds[4 * 1152];
    __shared__ float cbins[24];
    int blk = blockIdx.x;                 // 32 img * 32
    int img = blk >> 5;
    int pb  = blk & 31;
    int t = threadIdx.x;
    int wv = t >> 6, j = t & 63;
    int hpA = pb * 8 + wv * 2;            // row-pair indices [0,256)
    int hpB = hpA + 1;
    int h0 = 2 * hpA;                     // rows h0..h0+3
    float2* wlA = lds + wv * 1152;
    float2* wlB = wlA + 576;

    if (blk < 48) acc_rep[blk * 256 + t] = 0.0f;   // zero 16*768 replica floats
    if (t < 24) cbins[t] = 0.0f;
    __syncthreads();
    {                                     // folded sector map + per-block counts
        int idx = blk * 256 + t;          // idx = wm*512 + hm ; 1024*256 = full map
        int wm = idx >> 9, hm = idx & 511;
        int s = sector_id(hm, wm);
        mapT[idx] = (unsigned char)(s < 0 ? 255 : s);
        if (s >= 0) atomicAdd(&cbins[s], 1.0f);
    }

    const float* base = (img < 16) ? (pred + (size_t)img * 786432)
                                   : (tgt  + (size_t)(img - 16) * 786432);
    float whA0 = hannf(h0), whA1 = hannf(h0 + 1);
    float whB0 = hannf(h0 + 2), whB1 = hannf(h0 + 3);
    float2 va[8], vb[8];
    #pragma unroll
    for (int i = 0; i < 8; ++i) {
        int w = j + 64 * i;
        float ww = hannf(w);
        size_t off0 = (size_t)h0 * 512 + w;
        float l0 = lumaf(base, off0);
        float l1 = lumaf(base, off0 + 512);
        float l2 = lumaf(base, off0 + 1024);
        float l3 = lumaf(base, off0 + 1536);
        va[i] = make_float2(l0 * (whA0 * ww), l1 * (whA1 * ww));
        vb[i] = make_float2(l2 * (whB0 * ww), l3 * (whB1 * ww));
    }

    float sn, cs;
    __sincosf(-TWO_PI_F * (float)j / 512.0f, &sn, &cs);
    float2 tw0 = make_float2(cs, sn);
    __sincosf(-TWO_PI_F * (float)((j >> 3) << 3) / 512.0f, &sn, &cs);
    float2 tw1 = make_float2(cs, sn);

    fft512_pair(va, vb, wlA, wlB, tw0, tw1, j);   // R2-proven schedule

    size_t ibase = (size_t)img * 256;
    int partner = (64 - j) & 63;
    write_row_T(out4, ibase, hpA, va, partner, j);
    write_row_T(out4, ibase, hpB, vb, partner, j);

    __syncthreads();
    if (t < 24) cnt_u16[t * 1024 + blk] = (unsigned short)(int)cbins[t];
}

// ---------------- kernel 2: column FFT + log-mag + sector bins ----------------
// 1024 blocks x 4 waves; each BLOCK owns 8 CONTIGUOUS columns (128B/row, full
// cache lines, waves sharing a line co-resident on one CU -> R7's L2-friendly
// traffic), each WAVE runs the proven fft512_pair on 2 adjacent columns
// (R8's doubled wave count: 4096 waves = 16/CU ceiling, 4/SIMD).
__global__ __launch_bounds__(256, 4) void colfft_kernel(const float4* __restrict__ buf4,
                                                        const unsigned char* __restrict__ mapT,
                                                        float* __restrict__ acc_rep) {
    __shared__ float2 lds[4 * 1152];
    int blk = blockIdx.x;                 // [0,1024)
    int t = threadIdx.x;
    int wv = t >> 6, j = t & 63;
    int img = blk >> 5;                   // 32 blocks per img
    int b8  = blk & 31;                   // 8-column group within img
    int wA = b8 * 8 + wv * 2, wB = wA + 1;
    int pg = blk * 4 + wv;                // global pair id [0,4096)
    float2* wlA = lds + wv * 1152;
    float2* wlB = wlA + 576;

    const float4* b4 = buf4 + ((size_t)img * 256) * 256 + wA;
    float2 va[8], vb[8];
    #pragma unroll
    for (int i = 0; i < 8; ++i) {
        int h = j + 64 * i;
        const float4* row = b4 + (size_t)(h >> 1) * 256;
        float4 q0 = row[0], q1 = row[1];
        bool odd = (h & 1) != 0;
        va[i] = odd ? make_float2(q0.z, q0.w) : make_float2(q0.x, q0.y);
        vb[i] = odd ? make_float2(q1.z, q1.w) : make_float2(q1.x, q1.y);
    }

    float sn, cs;
    __sincosf(-TWO_PI_F * (float)j / 512.0f, &sn, &cs);
    float2 tw0 = make_float2(cs, sn);
    __sincosf(-TWO_PI_F * (float)((j >> 3) << 3) / 512.0f, &sn, &cs);
    float2 tw1 = make_float2(cs, sn);

    fft512_pair(va, vb, wlA, wlB, tw0, tw1, j);   // R2-proven schedule

    float* wb = (float*)wlA;              // FFT scratch dead -> 8 replicas x 25 bins
    #pragma unroll
    for (int i = 0; i < 4; ++i) { int ii = j + 64 * i; if (ii < 200) wb[ii] = 0.0f; }
    LGKM(0);

    constexpr int br[8] = {0,4,2,6,1,5,3,7};
    int rep = (j & 7) * 25;               // 25*r mod 32 distinct for r in [0,8)
    bool pairw = (wA == 0);               // stream A = packed real columns 0 & 256
    if (pairw) {
        // unpack two real-column FFTs: F0[k]=(Z[k]+conj(Z[-k]))/2,
        // F256[k]=(Z[k]-conj(Z[-k]))/(2i)
        int partner = (64 - j) & 63;
        const unsigned char* mwA1 = mapT + (size_t)256 * 512;   // col w=0   -> wm=256
        const unsigned char* mwA2 = mapT;                       // col w=256 -> wm=0
        #pragma unroll
        for (int c = 0; c < 8; ++c) {
            float2 zk = va[br[c]];
            float mx = __shfl(va[br[7 - c]].x, partner, 64);
            float my = __shfl(va[br[7 - c]].y, partner, 64);
            float2 zs = va[br[(8 - c) & 7]];
            float2 zm = make_float2(j == 0 ? zs.x : mx, j == 0 ? zs.y : my);
            float f0x = 0.5f*(zk.x+zm.x), f0y = 0.5f*(zk.y-zm.y);
            float f1x = 0.5f*(zk.y+zm.y), f1y = 0.5f*(zm.x-zk.x);
            float mag0 = __logf(1.0f + sqrtf(f0x*f0x + f0y*f0y));
            float mag1 = __logf(1.0f + sqrtf(f1x*f1x + f1y*f1y));
            int hm = j + 64 * ((c + 4) & 7);
            int s1 = mwA1[hm]; if (s1 < 24) atomicAdd(&wb[rep + s1], mag0);
            int s2 = mwA2[hm]; if (s2 < 24) atomicAdd(&wb[rep + s2], mag1);
        }
    } else {
        bin_col(va, mapT + (size_t)((wA + 256) & 511) * 512,
                    mapT + (size_t)((256 - wA) & 511) * 512, wb, rep, j);
    }
    bin_col(vb, mapT + (size_t)((wB + 256) & 511) * 512,
                mapT + (size_t)((256 - wB) & 511) * 512, wb, rep, j);
    LGKM(0);
    if (j < 24) {
        float sum = 0.0f;
        #pragma unroll
        for (int r = 0; r < 8; ++r) sum += wb[r * 25 + j];
        atomicAdd(&acc_rep[(pg & 15) * 768 + img * 24 + j], sum);
    }
}

// ---------------- kernel 3: reduce replicas/partials -> loss ----------------
__global__ __launch_bounds__(256) void final_kernel(const float* __restrict__ acc_rep,
                                                    const unsigned short* __restrict__ cnt_u16,
                                                    const float* __restrict__ rw,
                                                    float* __restrict__ out) {
    __shared__ float accs[768];
    __shared__ float cnts[24];
    __shared__ float ep[384], et[384], red[384];
    int t = threadIdx.x;
    for (int o = t; o < 768; o += 256) {           // sum 16 replicas (coalesced)
        float s = 0.0f;
        #pragma unroll
        for (int r = 0; r < 16; ++r) s += acc_rep[r * 768 + o];
        accs[o] = s;
    }
    if (t < 192) {                                 // counts: 24 sectors x 8 lanes
        int s = t >> 3, g = t & 7;
        const ushort4* p = (const ushort4*)(cnt_u16 + s * 1024 + g * 128);
        float sum = 0.0f;
        #pragma unroll
        for (int i = 0; i < 32; ++i) { ushort4 u = p[i]; sum += (float)(u.x + u.y + u.z + u.w); }
        sum += __shfl_down(sum, 4, 8);
        sum += __shfl_down(sum, 2, 8);
        sum += __shfl_down(sum, 1, 8);
        if (g == 0) cnts[s] = sum;
    }
    __syncthreads();
    for (int idx = t; idx < 384; idx += 256) {     // idx = b*24 + s, b in [0,16)
        int b = idx / 24, s = idx - b * 24;
        float cnt = fmaxf(cnts[s], 1e-6f);
        ep[idx] = accs[b * 24 + s] / cnt;
        et[idx] = accs[(16 + b) * 24 + s] / cnt;
    }
    __syncthreads();
    for (int idx = t; idx < 384; idx += 256) {
        int b = idx / 24, s = idx - b * 24, r = s >> 3;
        int gbase = b * 24 + r * 8;
        float sp = 0.0f, st = 0.0f;
        #pragma unroll
        for (int a = 0; a < 8; ++a) { sp += ep[gbase + a]; st += et[gbase + a]; }
        float pe = ep[idx] / fmaxf(sp, 1e-6f);
        float te = et[idx] / fmaxf(st, 1e-6f);
        float d = pe - te;
        red[idx] = sqrtf(d * d + 1e-6f) * rw[r];
    }
    __syncthreads();
    if (t < 128) red[t] += red[t + 128] + red[t + 256];
    __syncthreads();
    if (t < 64) {
        float vv = red[t] + red[t + 64];
        #pragma unroll
        for (int o = 32; o > 0; o >>= 1) vv += __shfl_down(vv, o, 64);
        if (t == 0) out[0] = vv / 384.0f;
    }
}

extern "C" void kernel_launch(void* const* d_in, const int* in_sizes, int n_in,
                              void* d_out, int out_size, void* d_ws, size_t ws_size,
                              hipStream_t stream) {
    const float* pred = (const float*)d_in[0];
    const float* tgt  = (const float*)d_in[1];
    const float* rw   = (const float*)d_in[2];

    char* ws = (char*)d_ws;
    float* acc_rep       = (float*)ws;                     // 16*768 floats = 49152 B
    unsigned short* cnt  = (unsigned short*)(ws + 49152);  // 24*1024*2     = 49152 B
    unsigned char* mapT  = (unsigned char*)(ws + 98304);   // 512*512       = 262144 B
    float4* buf4         = (float4*)(ws + 360448);         // 32*256*256*16 = 33.55 MB

    rowfft_kernel<<<1024, 256, 0, stream>>>(pred, tgt, buf4, mapT, cnt, acc_rep);
    colfft_kernel<<<1024, 256, 0, stream>>>(buf4, mapT, acc_rep);
    final_kernel<<<1, 256, 0, stream>>>(acc_rep, cnt, rw, (float*)d_out);
}